// Round 9
// baseline (335.981 us; speedup 1.0000x reference)
//
#include <hip/hip_runtime.h>
#include <cstdint>

// out = in + 0.1f * N(0,1) reproducing jax.random.normal(key(42), shape, f32).
// R6 PASS absmax 0.0078125 @232us; R8 (log1pf -> exact 1+t & v_log_f32) PASS
// same absmax @~180us. NUMERICS FROZEN since R8 (canary: absmax == 0.0078125).
// R9: within-probe A/B over disjoint halves, two dispatches:
//   A (GUARDED=false): R8's plain if/else erfinv          [control]
//   B (GUARDED=true):  unconditional main poly + __any()-guarded rare tail
// Per-lane float ops identical => bit-identical output; only schedule differs.

__device__ __forceinline__ uint32_t rotl32(uint32_t x, uint32_t r) {
    return __builtin_amdgcn_alignbit(x, x, 32u - r);   // 1x v_alignbit_b32
}

// Threefry-2x32, 20 rounds, key (0, 42); returns x0 ^ x1 (JAX 32-bit draw).
__device__ __forceinline__ uint32_t threefry_xor(uint32_t ctr_lo) {
    const uint32_t K0 = 0u;
    const uint32_t K1 = 42u;
    const uint32_t K2 = 0x1BD11BDAu ^ K0 ^ K1;   // 0x1BD11BF0
    uint32_t x1 = ctr_lo + K1;     // x0 = 0+K0 = 0; round-1 add folds
    uint32_t x0 = x1;
    x1 = rotl32(x1, 13); x1 ^= x0;
#define TF_R(r) { x0 += x1; x1 = rotl32(x1, r); x1 ^= x0; }
    TF_R(15) TF_R(26) TF_R(6)
    x0 += K1; x1 += K2 + 1u;
    TF_R(17) TF_R(29) TF_R(16) TF_R(24)
    x0 += K2; x1 += K0 + 2u;
    TF_R(13) TF_R(15) TF_R(26) TF_R(6)
    x0 += K0; x1 += K1 + 3u;
    TF_R(17) TF_R(29) TF_R(16) TF_R(24)
    x0 += K1; x1 += K2 + 4u;
    TF_R(13) TF_R(15) TF_R(26) TF_R(6)
    x0 += K2; x1 += K0 + 5u;
#undef TF_R
    return x0 ^ x1;
}

__device__ __forceinline__ float bits_to_u(uint32_t bits) {
    const float lo = -0.99999994f;               // nextafter(-1, 0)
    uint32_t fb = (bits >> 9) | 0x3F800000u;
    float f = __uint_as_float(fb) - 1.0f;
    float u = fmaf(f, 2.0f, lo);
    return fmaxf(u, lo);
}

__device__ __forceinline__ float erfinv_w(float x) {   // shared front-end
    float t = -(x * x);
    float s = 1.0f + t;                                // exact in tail (Sterbenz)
    return __log2f(s) * -0.693147182464599609375f;     // -ln2 * log2(s)
}

__device__ __forceinline__ float poly_main(float w) {
    w -= 2.5f;
    float p = 2.81022636e-08f;
    p = fmaf(p, w, 3.43273939e-07f);
    p = fmaf(p, w, -3.5233877e-06f);
    p = fmaf(p, w, -4.39150654e-06f);
    p = fmaf(p, w, 0.00021858087f);
    p = fmaf(p, w, -0.00125372503f);
    p = fmaf(p, w, -0.00417768164f);
    p = fmaf(p, w, 0.246640727f);
    p = fmaf(p, w, 1.50140941f);
    return p;
}

__device__ __forceinline__ float poly_tail(float w) {
    w = sqrtf(w) - 3.0f;
    float p = -0.000200214257f;
    p = fmaf(p, w, 0.000100950558f);
    p = fmaf(p, w, 0.00134934322f);
    p = fmaf(p, w, -0.00367342844f);
    p = fmaf(p, w, 0.00573950773f);
    p = fmaf(p, w, -0.0076224613f);
    p = fmaf(p, w, 0.00943887047f);
    p = fmaf(p, w, 1.00167406f);
    p = fmaf(p, w, 2.83297682f);
    return p;
}

template <bool GUARDED>
__global__ __launch_bounds__(256) void noise_add_kernel(
    const float* __restrict__ in, float* __restrict__ out, unsigned off) {
    unsigned t = off + blockIdx.x * blockDim.x + threadIdx.x;

    const float4 v = reinterpret_cast<const float4*>(in)[t];
    const uint32_t base = t * 4u;
    const float sqrt2 = 1.41421356f;    // 0x3FB504F3

    float r[4];
    const float vi[4] = {v.x, v.y, v.z, v.w};
#pragma unroll
    for (int k = 0; k < 4; ++k) {
        float x = bits_to_u(threefry_xor(base + (uint32_t)k));
        float w = erfinv_w(x);
        float p;
        if constexpr (GUARDED) {
            p = poly_main(w);                  // unconditional fast path
            bool tail = (w >= 5.0f);
            if (__any(tail)) {                 // wave-uniform, rare (~19%/site)
                if (tail) p = poly_tail(w);
            }
        } else {
            if (w < 5.0f) p = poly_main(w);    // R8 control
            else          p = poly_tail(w);
        }
        float nrm = sqrt2 * (p * x);
        r[k] = fmaf(0.1f, nrm, vi[k]);
    }

    float4 o;
    o.x = r[0]; o.y = r[1]; o.z = r[2]; o.w = r[3];
    reinterpret_cast<float4*>(out)[t] = o;
}

extern "C" void kernel_launch(void* const* d_in, const int* in_sizes, int n_in,
                              void* d_out, int out_size, void* d_ws, size_t ws_size,
                              hipStream_t stream) {
    const float* in = (const float*)d_in[0];
    float* out = (float*)d_out;
    const unsigned n    = (unsigned)in_sizes[0];   // 50331648
    const unsigned n4   = n / 4u;                  // 12582912
    const unsigned half = n4 / 2u;                 // 6291456 (div by 256)
    const unsigned block = 256;
    // Dispatch A: control (if/else), first half.
    noise_add_kernel<false><<<half / block, block, 0, stream>>>(in, out, 0u);
    // Dispatch B: guarded-tail, second half.
    noise_add_kernel<true><<<half / block, block, 0, stream>>>(in, out, half);
}